// Round 11
// baseline (117.133 us; speedup 1.0000x reference)
//
#include <hip/hip_runtime.h>
#include <math.h>

#define FDIM 128
#define NP 32                 // CSR partition blocks
#define NMAX 10240            // LDS capacity (N=10000)
static constexpr float SC2 = 0.17677669529663687f * 1.4426950408889634f; // (1/sqrt(32))*log2(e)
static constexpr float LN_EPS = 1e-5f;

__device__ __forceinline__ unsigned short f2bf(float f) {
    unsigned u = __float_as_uint(f);
    unsigned r = u + 0x7FFFu + ((u >> 16) & 1u);   // RNE
    return (unsigned short)(r >> 16);
}

// ---------------------------------------------------------------------------
// K1: fused 4-way GEMM (blockIdx.y 0..3) + LDS histogram (y==4, x<NP).
// GEMM thread-tile: 4 rows x 8 cols (halves LDS bytes/FMA vs 8x4).
// Q bf16 -> Qu[n][128]; K,V bf16 interleaved KVu[n][256]; R fp32.
// ---------------------------------------------------------------------------
__global__ __launch_bounds__(256) void gemm_hist_kernel(
    const float* __restrict__ nodes,
    const float* __restrict__ Wq, const float* __restrict__ Wk,
    const float* __restrict__ Wv, const float* __restrict__ Wr,
    const float* __restrict__ br,
    unsigned short* __restrict__ Qu, unsigned short* __restrict__ KVu,
    float* __restrict__ Rb, int N,
    const int* __restrict__ dst, int* __restrict__ bh, int E, int C)
{
    __shared__ __align__(16) char smem[NMAX * 4];   // 40KB: union of h[] / As[]
    const int tid = threadIdx.x;
    const int wi = blockIdx.y;

    if (wi == 4) {                    // ---- histogram partition ----
        const int p = blockIdx.x;
        if (p >= NP) return;
        int* h = (int*)smem;
        for (int i = tid; i < N; i += 256) h[i] = 0;
        __syncthreads();
        const int lo = p * C;
        const int hi = min(lo + C, E);
        const int n = hi - lo;
        if (n > 0) {
            if (((lo | E) & 3) == 0) {
                const int4* d4 = (const int4*)(dst + lo);
                const int n4 = n >> 2;
                for (int i = tid; i < n4; i += 256) {
                    int4 d = d4[i];
                    atomicAdd(&h[d.x], 1); atomicAdd(&h[d.y], 1);
                    atomicAdd(&h[d.z], 1); atomicAdd(&h[d.w], 1);
                }
                for (int i = lo + (n4 << 2) + tid; i < hi; i += 256)
                    atomicAdd(&h[dst[i]], 1);
            } else {
                for (int i = lo + tid; i < hi; i += 256)
                    atomicAdd(&h[dst[i]], 1);
            }
        }
        __syncthreads();
        for (int i = tid; i < N; i += 256) bh[p * N + i] = h[i];
        return;
    }

    // ---- GEMM partition ----
    float (*As)[FDIM] = (float(*)[FDIM])smem;       // 32KB of the 40KB
    const int row0 = blockIdx.x * 64;
    const float* __restrict__ W = (wi == 0) ? Wq : (wi == 1) ? Wk : (wi == 2) ? Wv : Wr;

    #pragma unroll
    for (int i = 0; i < 8; ++i) {
        int idx = tid + i * 256;          // 0..2047 float4s
        int r = idx >> 5, c4 = idx & 31;
        int gr = row0 + r;
        float4 v = make_float4(0.f, 0.f, 0.f, 0.f);
        if (gr < N) v = *reinterpret_cast<const float4*>(&nodes[(size_t)gr * FDIM + c4 * 4]);
        *reinterpret_cast<float4*>(&As[r][c4 * 4]) = v;
    }
    __syncthreads();

    const int cg = tid & 15;          // 16 col-groups of 8 cols
    const int rg = tid >> 4;          // 16 row-groups of 4 rows
    const int c0 = cg * 8;
    const int r0 = rg * 4;

    float acc[4][8];
    #pragma unroll
    for (int i = 0; i < 4; ++i)
        #pragma unroll
        for (int j = 0; j < 8; ++j) acc[i][j] = 0.f;

    #pragma unroll 4
    for (int k = 0; k < FDIM; k += 2) {
        const float4 wA0 = *reinterpret_cast<const float4*>(&W[k * FDIM + c0]);
        const float4 wA1 = *reinterpret_cast<const float4*>(&W[k * FDIM + c0 + 4]);
        const float4 wB0 = *reinterpret_cast<const float4*>(&W[(k + 1) * FDIM + c0]);
        const float4 wB1 = *reinterpret_cast<const float4*>(&W[(k + 1) * FDIM + c0 + 4]);
        float2 a[4];
        #pragma unroll
        for (int i = 0; i < 4; ++i)
            a[i] = *reinterpret_cast<const float2*>(&As[r0 + i][k]);
        #pragma unroll
        for (int i = 0; i < 4; ++i) {
            acc[i][0] += a[i].x * wA0.x + a[i].y * wB0.x;
            acc[i][1] += a[i].x * wA0.y + a[i].y * wB0.y;
            acc[i][2] += a[i].x * wA0.z + a[i].y * wB0.z;
            acc[i][3] += a[i].x * wA0.w + a[i].y * wB0.w;
            acc[i][4] += a[i].x * wA1.x + a[i].y * wB1.x;
            acc[i][5] += a[i].x * wA1.y + a[i].y * wB1.y;
            acc[i][6] += a[i].x * wA1.z + a[i].y * wB1.z;
            acc[i][7] += a[i].x * wA1.w + a[i].y * wB1.w;
        }
    }

    float bias[8];
    #pragma unroll
    for (int j = 0; j < 8; ++j) bias[j] = 0.f;
    if (wi == 3) {
        const float4 b0 = *reinterpret_cast<const float4*>(&br[c0]);
        const float4 b1 = *reinterpret_cast<const float4*>(&br[c0 + 4]);
        bias[0] = b0.x; bias[1] = b0.y; bias[2] = b0.z; bias[3] = b0.w;
        bias[4] = b1.x; bias[5] = b1.y; bias[6] = b1.z; bias[7] = b1.w;
    }

    #pragma unroll
    for (int i = 0; i < 4; ++i) {
        int gr = row0 + r0 + i;
        if (gr >= N) continue;
        if (wi == 3) {
            float4 o0 = make_float4(acc[i][0] + bias[0], acc[i][1] + bias[1],
                                    acc[i][2] + bias[2], acc[i][3] + bias[3]);
            float4 o1 = make_float4(acc[i][4] + bias[4], acc[i][5] + bias[5],
                                    acc[i][6] + bias[6], acc[i][7] + bias[7]);
            *reinterpret_cast<float4*>(&Rb[(size_t)gr * 128 + c0]) = o0;
            *reinterpret_cast<float4*>(&Rb[(size_t)gr * 128 + c0 + 4]) = o1;
        } else {
            ushort4 oa, ob;
            oa.x = f2bf(acc[i][0]); oa.y = f2bf(acc[i][1]);
            oa.z = f2bf(acc[i][2]); oa.w = f2bf(acc[i][3]);
            ob.x = f2bf(acc[i][4]); ob.y = f2bf(acc[i][5]);
            ob.z = f2bf(acc[i][6]); ob.w = f2bf(acc[i][7]);
            unsigned short* dp;
            if (wi == 0)      dp = &Qu[(size_t)gr * 128 + c0];
            else              dp = &KVu[(size_t)gr * 256 + ((wi == 2) ? 128 : 0) + c0];
            *reinterpret_cast<ushort4*>(dp) = oa;
            *reinterpret_cast<ushort4*>(dp + 4) = ob;
        }
    }
}

// ---------------------------------------------------------------------------
// K2a: deg[d] = sum_p bh[p][d]
// ---------------------------------------------------------------------------
__global__ __launch_bounds__(256) void deg_kernel(
    const int* __restrict__ bh, int* __restrict__ deg, int N)
{
    const int d = blockIdx.x * 256 + threadIdx.x;
    if (d < N) {
        int s = 0;
        #pragma unroll
        for (int p = 0; p < NP; ++p) s += bh[p * N + d];
        deg[d] = s;
    }
}

// ---------------------------------------------------------------------------
// K2b: single-block exclusive scan of deg -> rowptr
// ---------------------------------------------------------------------------
__global__ __launch_bounds__(1024) void scan_kernel(
    const int* __restrict__ deg, int* __restrict__ rowptr, int N)
{
    __shared__ int tot[NMAX];
    __shared__ int csum[1024];
    const int tid = threadIdx.x;

    for (int d = tid; d < N; d += 1024) tot[d] = deg[d];
    __syncthreads();

    const int CH = (N + 1023) / 1024;
    const int b = tid * CH;
    const int e = min(b + CH, N);
    int s = 0;
    for (int i = b; i < e; ++i) s += tot[i];
    csum[tid] = s;
    __syncthreads();
    for (int off = 1; off < 1024; off <<= 1) {
        int t = (tid >= off) ? csum[tid - off] : 0;
        __syncthreads();
        csum[tid] += t;
        __syncthreads();
    }
    int run = csum[tid] - s;
    for (int i = b; i < e; ++i) {
        const int t = tot[i];
        rowptr[i] = run;
        run += t;
    }
    if (tid == 1023) rowptr[N] = csum[1023];
}

// ---------------------------------------------------------------------------
// K2c: bh counts -> per-partition exclusive bases, in place.
// ---------------------------------------------------------------------------
__global__ __launch_bounds__(256) void base_kernel(
    int* __restrict__ bh, const int* __restrict__ rowptr, int N)
{
    const int d = blockIdx.x * 256 + threadIdx.x;
    if (d < N) {
        int c = rowptr[d];
        #pragma unroll
        for (int p = 0; p < NP; ++p) {
            const int cnt = bh[p * N + d];
            bh[p * N + d] = c;
            c += cnt;
        }
    }
}

// ---------------------------------------------------------------------------
// K3: scatter src ids into CSR slots (LDS cursors).
// ---------------------------------------------------------------------------
__global__ __launch_bounds__(256) void scatter_kernel(
    const int* __restrict__ src, const int* __restrict__ dst,
    const int* __restrict__ base, int* __restrict__ ssrc,
    int N, int E, int C)
{
    __shared__ int cur[NMAX];
    const int p = blockIdx.x, tid = threadIdx.x;
    for (int d = tid; d < N; d += 256) cur[d] = base[p * N + d];
    __syncthreads();

    const int lo = p * C;
    const int hi = min(lo + C, E);
    const int n = hi - lo;
    if (n <= 0) return;

    if (((lo | E) & 3) == 0) {
        const int4* s4 = (const int4*)(src + lo);
        const int4* d4 = (const int4*)(dst + lo);
        const int n4 = n >> 2;
        for (int i = tid; i < n4; i += 256) {
            int4 s = s4[i];
            int4 d = d4[i];
            int p0 = atomicAdd(&cur[d.x], 1); ssrc[p0] = s.x;
            int p1 = atomicAdd(&cur[d.y], 1); ssrc[p1] = s.y;
            int p2 = atomicAdd(&cur[d.z], 1); ssrc[p2] = s.z;
            int p3 = atomicAdd(&cur[d.w], 1); ssrc[p3] = s.w;
        }
        for (int i = lo + (n4 << 2) + tid; i < hi; i += 256) {
            int pos = atomicAdd(&cur[dst[i]], 1); ssrc[pos] = src[i];
        }
    } else {
        for (int i = lo + tid; i < hi; i += 256) {
            int pos = atomicAdd(&cur[dst[i]], 1); ssrc[pos] = src[i];
        }
    }
}

// ---------------------------------------------------------------------------
// K4: quarter-wave (16 lanes) per node; lane owns 8 dims (uint4 bf16 loads).
// Head = 4-lane group (dot reduce = xor 1,2). 4-edge batches, pipelined
// gathers + two-deep index prefetch. Residual + LayerNorm fused.
// ---------------------------------------------------------------------------
__global__ __launch_bounds__(256) void agg_kernel(
    const unsigned short* __restrict__ Qu, const unsigned short* __restrict__ KVu,
    const float* __restrict__ Rb,
    const int* __restrict__ rowptr, const int* __restrict__ ssrc,
    const float* __restrict__ gamma, const float* __restrict__ beta,
    float* __restrict__ out, int N)
{
    const int wave = threadIdx.x >> 6;
    const int lane = threadIdx.x & 63;
    const int qtr = lane >> 4;
    const int lq = lane & 15;
    const int n = blockIdx.x * 16 + wave * 4 + qtr;
    if (n >= N) return;
    const int d0 = lq * 8;

    // unpack q (8 bf16)
    const uint4 qu = *reinterpret_cast<const uint4*>(&Qu[(size_t)n * 128 + d0]);
    const float qf0 = __uint_as_float(qu.x << 16), qf1 = __uint_as_float(qu.x & 0xFFFF0000u);
    const float qf2 = __uint_as_float(qu.y << 16), qf3 = __uint_as_float(qu.y & 0xFFFF0000u);
    const float qf4 = __uint_as_float(qu.z << 16), qf5 = __uint_as_float(qu.z & 0xFFFF0000u);
    const float qf6 = __uint_as_float(qu.w << 16), qf7 = __uint_as_float(qu.w & 0xFFFF0000u);

    const int beg = rowptr[n];
    const int end = rowptr[n + 1];

    float4 A0a = make_float4(0.f, 0.f, 0.f, 0.f), A0b = A0a;
    float4 A1a = A0a, A1b = A0a, A2a = A0a, A2b = A0a, A3a = A0a, A3b = A0a;
    float L0 = 0.f, L1 = 0.f, L2 = 0.f, L3 = 0.f;

#define GATHER(S, NK, NV)                                                     \
    {                                                                         \
        const unsigned short* bp = &KVu[(size_t)(S) * 256 + d0];              \
        NK = *reinterpret_cast<const uint4*>(bp);                             \
        NV = *reinterpret_cast<const uint4*>(bp + 128);                       \
    }
#define STEP(KU, VU, Aa, Ab, L)                                               \
    {                                                                         \
        const float k0 = __uint_as_float((KU).x << 16), k1 = __uint_as_float((KU).x & 0xFFFF0000u); \
        const float k2 = __uint_as_float((KU).y << 16), k3 = __uint_as_float((KU).y & 0xFFFF0000u); \
        const float k4 = __uint_as_float((KU).z << 16), k5 = __uint_as_float((KU).z & 0xFFFF0000u); \
        const float k6 = __uint_as_float((KU).w << 16), k7 = __uint_as_float((KU).w & 0xFFFF0000u); \
        float p = qf0 * k0 + qf1 * k1 + qf2 * k2 + qf3 * k3                   \
                + qf4 * k4 + qf5 * k5 + qf6 * k6 + qf7 * k7;                  \
        p += __shfl_xor(p, 1);                                                \
        p += __shfl_xor(p, 2);                                                \
        const float e1 = exp2f(p * SC2);                                      \
        const float v0 = __uint_as_float((VU).x << 16), v1 = __uint_as_float((VU).x & 0xFFFF0000u); \
        const float v2 = __uint_as_float((VU).y << 16), v3 = __uint_as_float((VU).y & 0xFFFF0000u); \
        const float v4 = __uint_as_float((VU).z << 16), v5 = __uint_as_float((VU).z & 0xFFFF0000u); \
        const float v6 = __uint_as_float((VU).w << 16), v7 = __uint_as_float((VU).w & 0xFFFF0000u); \
        Aa.x += e1 * v0; Aa.y += e1 * v1; Aa.z += e1 * v2; Aa.w += e1 * v3;   \
        Ab.x += e1 * v4; Ab.y += e1 * v5; Ab.z += e1 * v6; Ab.w += e1 * v7;   \
        L += e1;                                                              \
    }

    uint4 nk0, nv0, nk1, nv1, nk2, nv2, nk3, nv3;
    int j = beg;
    const int nb = (end - beg) >> 2;
    if (nb > 0) {
        int c0i = ssrc[j], c1i = ssrc[j + 1], c2i = ssrc[j + 2], c3i = ssrc[j + 3];
        GATHER(c0i, nk0, nv0); GATHER(c1i, nk1, nv1);
        GATHER(c2i, nk2, nv2); GATHER(c3i, nk3, nv3);
        // prefetch next indices (ssrc padded by 8 -> safe)
        int x0 = ssrc[j + 4], x1 = ssrc[j + 5], x2 = ssrc[j + 6], x3 = ssrc[j + 7];
        for (int bi = 1; bi < nb; ++bi) {
            const uint4 ck0 = nk0, cv0 = nv0, ck1 = nk1, cv1 = nv1;
            const uint4 ck2 = nk2, cv2 = nv2, ck3 = nk3, cv3 = nv3;
            c0i = x0; c1i = x1; c2i = x2; c3i = x3;
            const int nbase = j + (bi + 1) * 4;           // prefetch (padded)
            x0 = ssrc[nbase]; x1 = ssrc[nbase + 1];
            x2 = ssrc[nbase + 2]; x3 = ssrc[nbase + 3];
            GATHER(c0i, nk0, nv0); GATHER(c1i, nk1, nv1);
            GATHER(c2i, nk2, nv2); GATHER(c3i, nk3, nv3);
            STEP(ck0, cv0, A0a, A0b, L0);
            STEP(ck1, cv1, A1a, A1b, L1);
            STEP(ck2, cv2, A2a, A2b, L2);
            STEP(ck3, cv3, A3a, A3b, L3);
        }
        STEP(nk0, nv0, A0a, A0b, L0);
        STEP(nk1, nv1, A1a, A1b, L1);
        STEP(nk2, nv2, A2a, A2b, L2);
        STEP(nk3, nv3, A3a, A3b, L3);
        j = beg + nb * 4;
    }
    for (; j < end; ++j) {
        const int s0 = ssrc[j];
        uint4 k0u, v0u;
        GATHER(s0, k0u, v0u);
        STEP(k0u, v0u, A0a, A0b, L0);
    }
#undef GATHER
#undef STEP

    const float L = (L0 + L1) + (L2 + L3);
    const float inv = 1.f / (L + 1e-12f);          // empty segment -> x = r
    const float4 ra = *reinterpret_cast<const float4*>(&Rb[(size_t)n * 128 + d0]);
    const float4 rb = *reinterpret_cast<const float4*>(&Rb[(size_t)n * 128 + d0 + 4]);
    float xa0 = ((A0a.x + A1a.x) + (A2a.x + A3a.x)) * inv + ra.x;
    float xa1 = ((A0a.y + A1a.y) + (A2a.y + A3a.y)) * inv + ra.y;
    float xa2 = ((A0a.z + A1a.z) + (A2a.z + A3a.z)) * inv + ra.z;
    float xa3 = ((A0a.w + A1a.w) + (A2a.w + A3a.w)) * inv + ra.w;
    float xb0 = ((A0b.x + A1b.x) + (A2b.x + A3b.x)) * inv + rb.x;
    float xb1 = ((A0b.y + A1b.y) + (A2b.y + A3b.y)) * inv + rb.y;
    float xb2 = ((A0b.z + A1b.z) + (A2b.z + A3b.z)) * inv + rb.z;
    float xb3 = ((A0b.w + A1b.w) + (A2b.w + A3b.w)) * inv + rb.w;

    // LayerNorm over 16 lanes x 8 dims
    float s1v = (xa0 + xa1 + xa2 + xa3) + (xb0 + xb1 + xb2 + xb3);
    float s2v = xa0 * xa0 + xa1 * xa1 + xa2 * xa2 + xa3 * xa3
              + xb0 * xb0 + xb1 * xb1 + xb2 * xb2 + xb3 * xb3;
    #pragma unroll
    for (int off = 8; off; off >>= 1) {
        s1v += __shfl_xor(s1v, off);
        s2v += __shfl_xor(s2v, off);
    }
    const float mu = s1v * (1.f / 128.f);
    float var = s2v * (1.f / 128.f) - mu * mu;
    var = fmaxf(var, 0.f);
    const float rs = rsqrtf(var + LN_EPS);

    const float4 ga = *reinterpret_cast<const float4*>(&gamma[d0]);
    const float4 gb = *reinterpret_cast<const float4*>(&gamma[d0 + 4]);
    const float4 ba = *reinterpret_cast<const float4*>(&beta[d0]);
    const float4 bb = *reinterpret_cast<const float4*>(&beta[d0 + 4]);
    float4 oa, ob;
    oa.x = ga.x * (xa0 - mu) * rs + ba.x;
    oa.y = ga.y * (xa1 - mu) * rs + ba.y;
    oa.z = ga.z * (xa2 - mu) * rs + ba.z;
    oa.w = ga.w * (xa3 - mu) * rs + ba.w;
    ob.x = gb.x * (xb0 - mu) * rs + bb.x;
    ob.y = gb.y * (xb1 - mu) * rs + bb.y;
    ob.z = gb.z * (xb2 - mu) * rs + bb.z;
    ob.w = gb.w * (xb3 - mu) * rs + bb.w;
    *reinterpret_cast<float4*>(&out[(size_t)n * 128 + d0]) = oa;
    *reinterpret_cast<float4*>(&out[(size_t)n * 128 + d0 + 4]) = ob;
}

// ---------------------------------------------------------------------------
extern "C" void kernel_launch(void* const* d_in, const int* in_sizes, int n_in,
                              void* d_out, int out_size, void* d_ws, size_t ws_size,
                              hipStream_t stream)
{
    const float* nodes = (const float*)d_in[0];
    const float* W_Q   = (const float*)d_in[1];
    const float* W_K   = (const float*)d_in[2];
    const float* W_V   = (const float*)d_in[3];
    const float* W_res = (const float*)d_in[4];
    const float* b_res = (const float*)d_in[5];
    const float* gamma = (const float*)d_in[6];
    const float* beta  = (const float*)d_in[7];
    const int*   eidx  = (const int*)d_in[8];

    const int N = in_sizes[0] / FDIM;
    const int E = in_sizes[8] / 2;
    const int* src = eidx;
    const int* dst = eidx + E;

    float* out = (float*)d_out;

    // workspace carve
    unsigned short* KVu = (unsigned short*)d_ws;              // N*256 bf16
    unsigned short* Qu  = KVu + (size_t)N * 256;              // N*128 bf16
    float* Rb = (float*)(Qu + (size_t)N * 128);               // N*128 f32
    int* bh     = (int*)(Rb + (size_t)N * 128);               // NP*N (counts -> bases)
    int* rowptr = bh + (size_t)NP * N;                        // N+1
    int* deg    = rowptr + (N + 1);                           // N
    int* ssrc   = deg + N;                                    // E + 8 (pad for prefetch)

    const int C = (((E + NP - 1) / NP) + 3) & ~3;             // chunk, mult of 4
    const int nG = (N + 63) / 64;
    const int nB = (N + 255) / 256;

    dim3 ggrid(nG, 5);                                        // y==4 -> histogram
    gemm_hist_kernel<<<ggrid, 256, 0, stream>>>(nodes, W_Q, W_K, W_V, W_res, b_res,
                                                Qu, KVu, Rb, N, dst, bh, E, C);
    deg_kernel<<<nB, 256, 0, stream>>>(bh, deg, N);
    scan_kernel<<<1, 1024, 0, stream>>>(deg, rowptr, N);
    base_kernel<<<nB, 256, 0, stream>>>(bh, rowptr, N);
    scatter_kernel<<<NP, 256, 0, stream>>>(src, dst, bh, ssrc, N, E, C);
    agg_kernel<<<(N + 15) / 16, 256, 0, stream>>>(Qu, KVu, Rb, rowptr, ssrc,
                                                  gamma, beta, out, N);
}

// Round 12
// 100.373 us; speedup vs baseline: 1.1670x; 1.1670x over previous
//
#include <hip/hip_runtime.h>
#include <math.h>

#define FDIM 128
#define NP 32                 // CSR partition blocks
#define NMAX 10240            // LDS capacity (N=10000)
static constexpr float SC2 = 0.17677669529663687f * 1.4426950408889634f; // (1/sqrt(32))*log2(e)
static constexpr float LN_EPS = 1e-5f;

typedef __attribute__((ext_vector_type(8))) short bf16x8;
typedef __attribute__((ext_vector_type(4))) float f32x4;

__device__ __forceinline__ unsigned short f2bf(float f) {
    unsigned u = __float_as_uint(f);
    unsigned r = u + 0x7FFFu + ((u >> 16) & 1u);   // RNE
    return (unsigned short)(r >> 16);
}

// ---------------------------------------------------------------------------
// K0: prep — nodes f32 -> bf16 (nodesb) ; W_{Q,K,V,res} -> W^T bf16 (Wt).
// blocks 0..639: nodes (2048 elems each). blocks 640..655: W^T (4 wi x 4 col-q).
// ---------------------------------------------------------------------------
__global__ __launch_bounds__(256) void prep_kernel(
    const float* __restrict__ nodes,
    const float* __restrict__ Wq, const float* __restrict__ Wk,
    const float* __restrict__ Wv, const float* __restrict__ Wr,
    unsigned short* __restrict__ nodesb, unsigned short* __restrict__ Wt, int N)
{
    const int tid = threadIdx.x;
    const int b = blockIdx.x;
    if (b < 640) {
        const int idx = b * 2048 + tid * 8;
        if (idx < N * FDIM) {
            const float4 f0 = *reinterpret_cast<const float4*>(&nodes[idx]);
            const float4 f1 = *reinterpret_cast<const float4*>(&nodes[idx + 4]);
            ushort4 o0, o1;
            o0.x = f2bf(f0.x); o0.y = f2bf(f0.y); o0.z = f2bf(f0.z); o0.w = f2bf(f0.w);
            o1.x = f2bf(f1.x); o1.y = f2bf(f1.y); o1.z = f2bf(f1.z); o1.w = f2bf(f1.w);
            *reinterpret_cast<ushort4*>(&nodesb[idx]) = o0;
            *reinterpret_cast<ushort4*>(&nodesb[idx + 4]) = o1;
        }
    } else {
        const int t = b - 640;              // 0..15
        const int wiW = t >> 2, q = t & 3;
        const float* __restrict__ W = (wiW == 0) ? Wq : (wiW == 1) ? Wk : (wiW == 2) ? Wv : Wr;
        const int c = q * 32 + (tid >> 3);  // 0..127
        const int k0 = (tid & 7) * 16;
        unsigned short* dp = &Wt[(size_t)wiW * 16384 + c * 128 + k0];
        #pragma unroll
        for (int kk = 0; kk < 16; ++kk)
            dp[kk] = f2bf(W[(k0 + kk) * FDIM + c]);
    }
}

// ---------------------------------------------------------------------------
// K1: fused MFMA GEMM (blockIdx.y 1..4) + LDS histogram (y==0, x<NP).
// GEMM: As (64x128 bf16) + W^T (128x128 bf16) staged in LDS (rows padded to
// 136 bf16). Wave w: rows w*16..+16; 8 col-tiles x 4 k-chunks of
// mfma_f32_16x16x32_bf16. C/D: col=lane&15, row=(lane>>4)*4+reg (m89).
// ---------------------------------------------------------------------------
__global__ __launch_bounds__(256) void gemm_hist_kernel(
    const unsigned short* __restrict__ nodesb,
    const unsigned short* __restrict__ Wt,
    const float* __restrict__ br,
    unsigned short* __restrict__ Qu, unsigned short* __restrict__ KVu,
    float* __restrict__ Rb, int N,
    const int* __restrict__ dst, int* __restrict__ bh, int E, int C)
{
    __shared__ __align__(16) char smem[52224];   // max(hist 40960, 17408+34816)
    const int tid = threadIdx.x;
    const int wi = blockIdx.y;

    if (wi == 0) {                    // ---- histogram partition ----
        const int p = blockIdx.x;
        if (p >= NP) return;
        int* h = (int*)smem;
        for (int i = tid; i < N; i += 256) h[i] = 0;
        __syncthreads();
        const int lo = p * C;
        const int hi = min(lo + C, E);
        const int n = hi - lo;
        if (n > 0) {
            if (((lo | E) & 3) == 0) {
                const int4* d4 = (const int4*)(dst + lo);
                const int n4 = n >> 2;
                for (int i = tid; i < n4; i += 256) {
                    int4 d = d4[i];
                    atomicAdd(&h[d.x], 1); atomicAdd(&h[d.y], 1);
                    atomicAdd(&h[d.z], 1); atomicAdd(&h[d.w], 1);
                }
                for (int i = lo + (n4 << 2) + tid; i < hi; i += 256)
                    atomicAdd(&h[dst[i]], 1);
            } else {
                for (int i = lo + tid; i < hi; i += 256)
                    atomicAdd(&h[dst[i]], 1);
            }
        }
        __syncthreads();
        for (int i = tid; i < N; i += 256) bh[p * N + i] = h[i];
        return;
    }

    // ---- GEMM partition ----
    const int gw = wi - 1;            // 0=Q, 1=K, 2=V, 3=R
    const int row0 = blockIdx.x * 64;
    unsigned short (*As)[136] = (unsigned short(*)[136])smem;            // 64 rows
    unsigned short (*Ws)[136] = (unsigned short(*)[136])(smem + 64 * 272);// 128 rows

    // stage As: 64 rows x 16 chunks of 16B
    #pragma unroll
    for (int i = 0; i < 4; ++i) {
        const int idx = tid + i * 256;           // 0..1023
        const int r = idx >> 4, ch = idx & 15;
        const int gr = row0 + r;
        uint4 v = make_uint4(0u, 0u, 0u, 0u);
        if (gr < N) v = *reinterpret_cast<const uint4*>(&nodesb[(size_t)gr * 128 + ch * 8]);
        *reinterpret_cast<uint4*>(&As[r][ch * 8]) = v;
    }
    // stage W^T: 128 rows x 16 chunks
    const unsigned short* Wg = &Wt[(size_t)gw * 16384];
    #pragma unroll
    for (int i = 0; i < 8; ++i) {
        const int idx = tid + i * 256;           // 0..2047
        const int r = idx >> 4, ch = idx & 15;
        const uint4 v = *reinterpret_cast<const uint4*>(&Wg[r * 128 + ch * 8]);
        *reinterpret_cast<uint4*>(&Ws[r][ch * 8]) = v;
    }
    __syncthreads();

    const int w = tid >> 6;           // wave 0..3 -> rows w*16..
    const int l = tid & 63;
    const int lr = l & 15;
    const int lh = l >> 4;

    f32x4 acc[8];
    #pragma unroll
    for (int ct = 0; ct < 8; ++ct) acc[ct] = (f32x4){0.f, 0.f, 0.f, 0.f};

    #pragma unroll
    for (int kc = 0; kc < 4; ++kc) {
        const bf16x8 a = *reinterpret_cast<const bf16x8*>(&As[w * 16 + lr][kc * 32 + lh * 8]);
        #pragma unroll
        for (int ct = 0; ct < 8; ++ct) {
            const bf16x8 bb = *reinterpret_cast<const bf16x8*>(&Ws[ct * 16 + lr][kc * 32 + lh * 8]);
            acc[ct] = __builtin_amdgcn_mfma_f32_16x16x32_bf16(a, bb, acc[ct], 0, 0, 0);
        }
    }

    // epilogue: col = ct*16 + lr, row = row0 + w*16 + lh*4 + r
    const int rbase = row0 + w * 16 + lh * 4;
    #pragma unroll
    for (int ct = 0; ct < 8; ++ct) {
        const int col = ct * 16 + lr;
        float bc = 0.f;
        if (gw == 3) bc = br[col];
        #pragma unroll
        for (int r = 0; r < 4; ++r) {
            const int row = rbase + r;
            if (row >= N) continue;
            const float val = acc[ct][r];
            if (gw == 0)      Qu[(size_t)row * 128 + col] = f2bf(val);
            else if (gw == 1) KVu[(size_t)row * 256 + col] = f2bf(val);
            else if (gw == 2) KVu[(size_t)row * 256 + 128 + col] = f2bf(val);
            else              Rb[(size_t)row * 128 + col] = val + bc;
        }
    }
}

// ---------------------------------------------------------------------------
// K2a: deg[d] = sum_p bh[p][d]
// ---------------------------------------------------------------------------
__global__ __launch_bounds__(256) void deg_kernel(
    const int* __restrict__ bh, int* __restrict__ deg, int N)
{
    const int d = blockIdx.x * 256 + threadIdx.x;
    if (d < N) {
        int s = 0;
        #pragma unroll
        for (int p = 0; p < NP; ++p) s += bh[p * N + d];
        deg[d] = s;
    }
}

// ---------------------------------------------------------------------------
// K2b: single-block exclusive scan of deg -> rowptr
// ---------------------------------------------------------------------------
__global__ __launch_bounds__(1024) void scan_kernel(
    const int* __restrict__ deg, int* __restrict__ rowptr, int N)
{
    __shared__ int tot[NMAX];
    __shared__ int csum[1024];
    const int tid = threadIdx.x;

    for (int d = tid; d < N; d += 1024) tot[d] = deg[d];
    __syncthreads();

    const int CH = (N + 1023) / 1024;
    const int b = tid * CH;
    const int e = min(b + CH, N);
    int s = 0;
    for (int i = b; i < e; ++i) s += tot[i];
    csum[tid] = s;
    __syncthreads();
    for (int off = 1; off < 1024; off <<= 1) {
        int t = (tid >= off) ? csum[tid - off] : 0;
        __syncthreads();
        csum[tid] += t;
        __syncthreads();
    }
    int run = csum[tid] - s;
    for (int i = b; i < e; ++i) {
        const int t = tot[i];
        rowptr[i] = run;
        run += t;
    }
    if (tid == 1023) rowptr[N] = csum[1023];
}

// ---------------------------------------------------------------------------
// K2c: bh counts -> per-partition exclusive bases, in place.
// ---------------------------------------------------------------------------
__global__ __launch_bounds__(256) void base_kernel(
    int* __restrict__ bh, const int* __restrict__ rowptr, int N)
{
    const int d = blockIdx.x * 256 + threadIdx.x;
    if (d < N) {
        int c = rowptr[d];
        #pragma unroll
        for (int p = 0; p < NP; ++p) {
            const int cnt = bh[p * N + d];
            bh[p * N + d] = c;
            c += cnt;
        }
    }
}

// ---------------------------------------------------------------------------
// K3: scatter src ids into CSR slots (LDS cursors).
// ---------------------------------------------------------------------------
__global__ __launch_bounds__(256) void scatter_kernel(
    const int* __restrict__ src, const int* __restrict__ dst,
    const int* __restrict__ base, int* __restrict__ ssrc,
    int N, int E, int C)
{
    __shared__ int cur[NMAX];
    const int p = blockIdx.x, tid = threadIdx.x;
    for (int d = tid; d < N; d += 256) cur[d] = base[p * N + d];
    __syncthreads();

    const int lo = p * C;
    const int hi = min(lo + C, E);
    const int n = hi - lo;
    if (n <= 0) return;

    if (((lo | E) & 3) == 0) {
        const int4* s4 = (const int4*)(src + lo);
        const int4* d4 = (const int4*)(dst + lo);
        const int n4 = n >> 2;
        for (int i = tid; i < n4; i += 256) {
            int4 s = s4[i];
            int4 d = d4[i];
            int p0 = atomicAdd(&cur[d.x], 1); ssrc[p0] = s.x;
            int p1 = atomicAdd(&cur[d.y], 1); ssrc[p1] = s.y;
            int p2 = atomicAdd(&cur[d.z], 1); ssrc[p2] = s.z;
            int p3 = atomicAdd(&cur[d.w], 1); ssrc[p3] = s.w;
        }
        for (int i = lo + (n4 << 2) + tid; i < hi; i += 256) {
            int pos = atomicAdd(&cur[dst[i]], 1); ssrc[pos] = src[i];
        }
    } else {
        for (int i = lo + tid; i < hi; i += 256) {
            int pos = atomicAdd(&cur[dst[i]], 1); ssrc[pos] = src[i];
        }
    }
}

// ---------------------------------------------------------------------------
// K4: quarter-wave (16 lanes) per node; lane owns 8 dims (uint4 bf16 loads).
// Head = 4-lane group (dot reduce = xor 1,2). 4-edge batches, pipelined
// gathers + two-deep index prefetch. Residual + LayerNorm fused.
// ---------------------------------------------------------------------------
__global__ __launch_bounds__(256) void agg_kernel(
    const unsigned short* __restrict__ Qu, const unsigned short* __restrict__ KVu,
    const float* __restrict__ Rb,
    const int* __restrict__ rowptr, const int* __restrict__ ssrc,
    const float* __restrict__ gamma, const float* __restrict__ beta,
    float* __restrict__ out, int N)
{
    const int wave = threadIdx.x >> 6;
    const int lane = threadIdx.x & 63;
    const int qtr = lane >> 4;
    const int lq = lane & 15;
    const int n = blockIdx.x * 16 + wave * 4 + qtr;
    if (n >= N) return;
    const int d0 = lq * 8;

    // unpack q (8 bf16)
    const uint4 qu = *reinterpret_cast<const uint4*>(&Qu[(size_t)n * 128 + d0]);
    const float qf0 = __uint_as_float(qu.x << 16), qf1 = __uint_as_float(qu.x & 0xFFFF0000u);
    const float qf2 = __uint_as_float(qu.y << 16), qf3 = __uint_as_float(qu.y & 0xFFFF0000u);
    const float qf4 = __uint_as_float(qu.z << 16), qf5 = __uint_as_float(qu.z & 0xFFFF0000u);
    const float qf6 = __uint_as_float(qu.w << 16), qf7 = __uint_as_float(qu.w & 0xFFFF0000u);

    const int beg = rowptr[n];
    const int end = rowptr[n + 1];

    float4 A0a = make_float4(0.f, 0.f, 0.f, 0.f), A0b = A0a;
    float4 A1a = A0a, A1b = A0a, A2a = A0a, A2b = A0a, A3a = A0a, A3b = A0a;
    float L0 = 0.f, L1 = 0.f, L2 = 0.f, L3 = 0.f;

#define GATHER(S, NK, NV)                                                     \
    {                                                                         \
        const unsigned short* bp = &KVu[(size_t)(S) * 256 + d0];              \
        NK = *reinterpret_cast<const uint4*>(bp);                             \
        NV = *reinterpret_cast<const uint4*>(bp + 128);                       \
    }
#define STEP(KU, VU, Aa, Ab, L)                                               \
    {                                                                         \
        const float k0 = __uint_as_float((KU).x << 16), k1 = __uint_as_float((KU).x & 0xFFFF0000u); \
        const float k2 = __uint_as_float((KU).y << 16), k3 = __uint_as_float((KU).y & 0xFFFF0000u); \
        const float k4 = __uint_as_float((KU).z << 16), k5 = __uint_as_float((KU).z & 0xFFFF0000u); \
        const float k6 = __uint_as_float((KU).w << 16), k7 = __uint_as_float((KU).w & 0xFFFF0000u); \
        float p = qf0 * k0 + qf1 * k1 + qf2 * k2 + qf3 * k3                   \
                + qf4 * k4 + qf5 * k5 + qf6 * k6 + qf7 * k7;                  \
        p += __shfl_xor(p, 1);                                                \
        p += __shfl_xor(p, 2);                                                \
        const float e1 = exp2f(p * SC2);                                      \
        const float v0 = __uint_as_float((VU).x << 16), v1 = __uint_as_float((VU).x & 0xFFFF0000u); \
        const float v2 = __uint_as_float((VU).y << 16), v3 = __uint_as_float((VU).y & 0xFFFF0000u); \
        const float v4 = __uint_as_float((VU).z << 16), v5 = __uint_as_float((VU).z & 0xFFFF0000u); \
        const float v6 = __uint_as_float((VU).w << 16), v7 = __uint_as_float((VU).w & 0xFFFF0000u); \
        Aa.x += e1 * v0; Aa.y += e1 * v1; Aa.z += e1 * v2; Aa.w += e1 * v3;   \
        Ab.x += e1 * v4; Ab.y += e1 * v5; Ab.z += e1 * v6; Ab.w += e1 * v7;   \
        L += e1;                                                              \
    }

    uint4 nk0, nv0, nk1, nv1, nk2, nv2, nk3, nv3;
    int j = beg;
    const int nb = (end - beg) >> 2;
    if (nb > 0) {
        int c0i = ssrc[j], c1i = ssrc[j + 1], c2i = ssrc[j + 2], c3i = ssrc[j + 3];
        GATHER(c0i, nk0, nv0); GATHER(c1i, nk1, nv1);
        GATHER(c2i, nk2, nv2); GATHER(c3i, nk3, nv3);
        // prefetch next indices (ssrc padded by 8 -> safe)
        int x0 = ssrc[j + 4], x1 = ssrc[j + 5], x2 = ssrc[j + 6], x3 = ssrc[j + 7];
        for (int bi = 1; bi < nb; ++bi) {
            const uint4 ck0 = nk0, cv0 = nv0, ck1 = nk1, cv1 = nv1;
            const uint4 ck2 = nk2, cv2 = nv2, ck3 = nk3, cv3 = nv3;
            c0i = x0; c1i = x1; c2i = x2; c3i = x3;
            const int nbase = j + (bi + 1) * 4;           // prefetch (padded)
            x0 = ssrc[nbase]; x1 = ssrc[nbase + 1];
            x2 = ssrc[nbase + 2]; x3 = ssrc[nbase + 3];
            GATHER(c0i, nk0, nv0); GATHER(c1i, nk1, nv1);
            GATHER(c2i, nk2, nv2); GATHER(c3i, nk3, nv3);
            STEP(ck0, cv0, A0a, A0b, L0);
            STEP(ck1, cv1, A1a, A1b, L1);
            STEP(ck2, cv2, A2a, A2b, L2);
            STEP(ck3, cv3, A3a, A3b, L3);
        }
        STEP(nk0, nv0, A0a, A0b, L0);
        STEP(nk1, nv1, A1a, A1b, L1);
        STEP(nk2, nv2, A2a, A2b, L2);
        STEP(nk3, nv3, A3a, A3b, L3);
        j = beg + nb * 4;
    }
    for (; j < end; ++j) {
        const int s0 = ssrc[j];
        uint4 k0u, v0u;
        GATHER(s0, k0u, v0u);
        STEP(k0u, v0u, A0a, A0b, L0);
    }
#undef GATHER
#undef STEP

    const float L = (L0 + L1) + (L2 + L3);
    const float inv = 1.f / (L + 1e-12f);          // empty segment -> x = r
    const float4 ra = *reinterpret_cast<const float4*>(&Rb[(size_t)n * 128 + d0]);
    const float4 rb = *reinterpret_cast<const float4*>(&Rb[(size_t)n * 128 + d0 + 4]);
    float xa0 = ((A0a.x + A1a.x) + (A2a.x + A3a.x)) * inv + ra.x;
    float xa1 = ((A0a.y + A1a.y) + (A2a.y + A3a.y)) * inv + ra.y;
    float xa2 = ((A0a.z + A1a.z) + (A2a.z + A3a.z)) * inv + ra.z;
    float xa3 = ((A0a.w + A1a.w) + (A2a.w + A3a.w)) * inv + ra.w;
    float xb0 = ((A0b.x + A1b.x) + (A2b.x + A3b.x)) * inv + rb.x;
    float xb1 = ((A0b.y + A1b.y) + (A2b.y + A3b.y)) * inv + rb.y;
    float xb2 = ((A0b.z + A1b.z) + (A2b.z + A3b.z)) * inv + rb.z;
    float xb3 = ((A0b.w + A1b.w) + (A2b.w + A3b.w)) * inv + rb.w;

    // LayerNorm over 16 lanes x 8 dims
    float s1v = (xa0 + xa1 + xa2 + xa3) + (xb0 + xb1 + xb2 + xb3);
    float s2v = xa0 * xa0 + xa1 * xa1 + xa2 * xa2 + xa3 * xa3
              + xb0 * xb0 + xb1 * xb1 + xb2 * xb2 + xb3 * xb3;
    #pragma unroll
    for (int off = 8; off; off >>= 1) {
        s1v += __shfl_xor(s1v, off);
        s2v += __shfl_xor(s2v, off);
    }
    const float mu = s1v * (1.f / 128.f);
    float var = s2v * (1.f / 128.f) - mu * mu;
    var = fmaxf(var, 0.f);
    const float rs = rsqrtf(var + LN_EPS);

    const float4 ga = *reinterpret_cast<const float4*>(&gamma[d0]);
    const float4 gb = *reinterpret_cast<const float4*>(&gamma[d0 + 4]);
    const float4 ba = *reinterpret_cast<const float4*>(&beta[d0]);
    const float4 bb = *reinterpret_cast<const float4*>(&beta[d0 + 4]);
    float4 oa, ob;
    oa.x = ga.x * (xa0 - mu) * rs + ba.x;
    oa.y = ga.y * (xa1 - mu) * rs + ba.y;
    oa.z = ga.z * (xa2 - mu) * rs + ba.z;
    oa.w = ga.w * (xa3 - mu) * rs + ba.w;
    ob.x = gb.x * (xb0 - mu) * rs + bb.x;
    ob.y = gb.y * (xb1 - mu) * rs + bb.y;
    ob.z = gb.z * (xb2 - mu) * rs + bb.z;
    ob.w = gb.w * (xb3 - mu) * rs + bb.w;
    *reinterpret_cast<float4*>(&out[(size_t)n * 128 + d0]) = oa;
    *reinterpret_cast<float4*>(&out[(size_t)n * 128 + d0 + 4]) = ob;
}

// ---------------------------------------------------------------------------
extern "C" void kernel_launch(void* const* d_in, const int* in_sizes, int n_in,
                              void* d_out, int out_size, void* d_ws, size_t ws_size,
                              hipStream_t stream)
{
    const float* nodes = (const float*)d_in[0];
    const float* W_Q   = (const float*)d_in[1];
    const float* W_K   = (const float*)d_in[2];
    const float* W_V   = (const float*)d_in[3];
    const float* W_res = (const float*)d_in[4];
    const float* b_res = (const float*)d_in[5];
    const float* gamma = (const float*)d_in[6];
    const float* beta  = (const float*)d_in[7];
    const int*   eidx  = (const int*)d_in[8];

    const int N = in_sizes[0] / FDIM;
    const int E = in_sizes[8] / 2;
    const int* src = eidx;
    const int* dst = eidx + E;

    float* out = (float*)d_out;

    // workspace carve
    unsigned short* KVu    = (unsigned short*)d_ws;           // N*256 bf16
    unsigned short* Qu     = KVu + (size_t)N * 256;           // N*128 bf16
    unsigned short* nodesb = Qu + (size_t)N * 128;            // N*128 bf16
    unsigned short* Wt     = nodesb + (size_t)N * 128;        // 4*128*128 bf16
    float* Rb   = (float*)(Wt + 4 * 16384);                   // N*128 f32
    int* bh     = (int*)(Rb + (size_t)N * 128);               // NP*N (counts -> bases)
    int* rowptr = bh + (size_t)NP * N;                        // N+1
    int* deg    = rowptr + (N + 1);                           // N
    int* ssrc   = deg + N;                                    // E + 8 (pad for prefetch)

    const int C = (((E + NP - 1) / NP) + 3) & ~3;             // chunk, mult of 4
    const int nG = (N + 63) / 64;
    const int nB = (N + 255) / 256;

    prep_kernel<<<656, 256, 0, stream>>>(nodes, W_Q, W_K, W_V, W_res, nodesb, Wt, N);

    dim3 ggrid(nG, 5);                                        // y==0 -> histogram
    gemm_hist_kernel<<<ggrid, 256, 0, stream>>>(nodesb, Wt, b_res,
                                                Qu, KVu, Rb, N, dst, bh, E, C);
    deg_kernel<<<nB, 256, 0, stream>>>(bh, deg, N);
    scan_kernel<<<1, 1024, 0, stream>>>(deg, rowptr, N);
    base_kernel<<<nB, 256, 0, stream>>>(bh, rowptr, N);
    scatter_kernel<<<NP, 256, 0, stream>>>(src, dst, bh, ssrc, N, E, C);
    agg_kernel<<<(N + 15) / 16, 256, 0, stream>>>(Qu, KVu, Rb, rowptr, ssrc,
                                                  gamma, beta, out, N);
}

// Round 13
// 95.285 us; speedup vs baseline: 1.2293x; 1.0534x over previous
//
#include <hip/hip_runtime.h>
#include <math.h>

#define FDIM 128
#define NP 64                 // CSR partition blocks
#define NMAX 10240            // LDS capacity (N=10000)
static constexpr float SC2 = 0.17677669529663687f * 1.4426950408889634f; // (1/sqrt(32))*log2(e)
static constexpr float LN_EPS = 1e-5f;

typedef __attribute__((ext_vector_type(8))) short bf16x8;
typedef __attribute__((ext_vector_type(4))) float f32x4;

__device__ __forceinline__ unsigned short f2bf(float f) {
    unsigned u = __float_as_uint(f);
    unsigned r = u + 0x7FFFu + ((u >> 16) & 1u);   // RNE
    return (unsigned short)(r >> 16);
}

// ---------------------------------------------------------------------------
// K0: prep — W_{Q,K,V,res} f32 -> W^T bf16 (Wt[wi][c][k]). 16 blocks.
// ---------------------------------------------------------------------------
__global__ __launch_bounds__(256) void prep_kernel(
    const float* __restrict__ Wq, const float* __restrict__ Wk,
    const float* __restrict__ Wv, const float* __restrict__ Wr,
    unsigned short* __restrict__ Wt)
{
    const int tid = threadIdx.x;
    const int t = blockIdx.x;           // 0..15
    const int wiW = t >> 2, q = t & 3;
    const float* __restrict__ W = (wiW == 0) ? Wq : (wiW == 1) ? Wk : (wiW == 2) ? Wv : Wr;
    const int c = q * 32 + (tid >> 3);  // 0..127
    const int k0 = (tid & 7) * 16;
    unsigned short* dp = &Wt[(size_t)wiW * 16384 + c * 128 + k0];
    #pragma unroll
    for (int kk = 0; kk < 16; ++kk)
        dp[kk] = f2bf(W[(k0 + kk) * FDIM + c]);
}

// ---------------------------------------------------------------------------
// K1: fused MFMA GEMM (blockIdx.y 1..4) + LDS histogram (y==0, x<NP).
// GEMM: As (64x128, staged f32->bf16 inline) + W^T (128x128 bf16) in LDS
// (rows padded to 136). Wave w: rows w*16..+16; 8 col-tiles x 4 k-chunks of
// mfma_f32_16x16x32_bf16. C/D: col=lane&15, row=(lane>>4)*4+reg (m89).
// ---------------------------------------------------------------------------
__global__ __launch_bounds__(256) void gemm_hist_kernel(
    const float* __restrict__ nodes,
    const unsigned short* __restrict__ Wt,
    const float* __restrict__ br,
    unsigned short* __restrict__ Qu, unsigned short* __restrict__ KVu,
    float* __restrict__ Rb, int N,
    const int* __restrict__ dst, int* __restrict__ bh, int E, int C)
{
    __shared__ __align__(16) char smem[52224];   // max(hist 40960, 17408+34816)
    const int tid = threadIdx.x;
    const int wi = blockIdx.y;

    if (wi == 0) {                    // ---- histogram partition ----
        const int p = blockIdx.x;
        if (p >= NP) return;
        int* h = (int*)smem;
        for (int i = tid; i < N; i += 256) h[i] = 0;
        __syncthreads();
        const int lo = p * C;
        const int hi = min(lo + C, E);
        const int n = hi - lo;
        if (n > 0) {
            if (((lo | E) & 3) == 0) {
                const int4* d4 = (const int4*)(dst + lo);
                const int n4 = n >> 2;
                for (int i = tid; i < n4; i += 256) {
                    int4 d = d4[i];
                    atomicAdd(&h[d.x], 1); atomicAdd(&h[d.y], 1);
                    atomicAdd(&h[d.z], 1); atomicAdd(&h[d.w], 1);
                }
                for (int i = lo + (n4 << 2) + tid; i < hi; i += 256)
                    atomicAdd(&h[dst[i]], 1);
            } else {
                for (int i = lo + tid; i < hi; i += 256)
                    atomicAdd(&h[dst[i]], 1);
            }
        }
        __syncthreads();
        for (int i = tid; i < N; i += 256) bh[p * N + i] = h[i];
        return;
    }

    // ---- GEMM partition ----
    const int gw = wi - 1;            // 0=Q, 1=K, 2=V, 3=R
    const int row0 = blockIdx.x * 64;
    unsigned short (*As)[136] = (unsigned short(*)[136])smem;            // 64 rows
    unsigned short (*Ws)[136] = (unsigned short(*)[136])(smem + 64 * 272);// 128 rows

    // stage As: 64 rows x 128 cols, f32 -> bf16 inline
    #pragma unroll
    for (int i = 0; i < 8; ++i) {
        const int idx = tid + i * 256;           // 0..2047 float4s
        const int r = idx >> 5, c4 = idx & 31;
        const int gr = row0 + r;
        float4 v = make_float4(0.f, 0.f, 0.f, 0.f);
        if (gr < N) v = *reinterpret_cast<const float4*>(&nodes[(size_t)gr * FDIM + c4 * 4]);
        ushort4 o;
        o.x = f2bf(v.x); o.y = f2bf(v.y); o.z = f2bf(v.z); o.w = f2bf(v.w);
        *reinterpret_cast<ushort4*>(&As[r][c4 * 4]) = o;
    }
    // stage W^T: 128 rows x 16 chunks of 16B (already bf16)
    const unsigned short* Wg = &Wt[(size_t)gw * 16384];
    #pragma unroll
    for (int i = 0; i < 8; ++i) {
        const int idx = tid + i * 256;           // 0..2047
        const int r = idx >> 4, ch = idx & 15;
        const uint4 v = *reinterpret_cast<const uint4*>(&Wg[r * 128 + ch * 8]);
        *reinterpret_cast<uint4*>(&Ws[r][ch * 8]) = v;
    }
    __syncthreads();

    const int w = tid >> 6;           // wave 0..3 -> rows w*16..
    const int l = tid & 63;
    const int lr = l & 15;
    const int lh = l >> 4;

    f32x4 acc[8];
    #pragma unroll
    for (int ct = 0; ct < 8; ++ct) acc[ct] = (f32x4){0.f, 0.f, 0.f, 0.f};

    #pragma unroll
    for (int kc = 0; kc < 4; ++kc) {
        const bf16x8 a = *reinterpret_cast<const bf16x8*>(&As[w * 16 + lr][kc * 32 + lh * 8]);
        #pragma unroll
        for (int ct = 0; ct < 8; ++ct) {
            const bf16x8 bb = *reinterpret_cast<const bf16x8*>(&Ws[ct * 16 + lr][kc * 32 + lh * 8]);
            acc[ct] = __builtin_amdgcn_mfma_f32_16x16x32_bf16(a, bb, acc[ct], 0, 0, 0);
        }
    }

    // epilogue: col = ct*16 + lr, row = row0 + w*16 + lh*4 + r
    const int rbase = row0 + w * 16 + lh * 4;
    #pragma unroll
    for (int ct = 0; ct < 8; ++ct) {
        const int col = ct * 16 + lr;
        float bc = 0.f;
        if (gw == 3) bc = br[col];
        #pragma unroll
        for (int r = 0; r < 4; ++r) {
            const int row = rbase + r;
            if (row >= N) continue;
            const float val = acc[ct][r];
            if (gw == 0)      Qu[(size_t)row * 128 + col] = f2bf(val);
            else if (gw == 1) KVu[(size_t)row * 256 + col] = f2bf(val);
            else if (gw == 2) KVu[(size_t)row * 256 + 128 + col] = f2bf(val);
            else              Rb[(size_t)row * 128 + col] = val + bc;
        }
    }
}

// ---------------------------------------------------------------------------
// K2a: deg[d] = sum_p bh[p][d]
// ---------------------------------------------------------------------------
__global__ __launch_bounds__(256) void deg_kernel(
    const int* __restrict__ bh, int* __restrict__ deg, int N)
{
    const int d = blockIdx.x * 256 + threadIdx.x;
    if (d < N) {
        int s = 0;
        #pragma unroll
        for (int p = 0; p < NP; ++p) s += bh[p * N + d];
        deg[d] = s;
    }
}

// ---------------------------------------------------------------------------
// K2b: single-block exclusive scan of deg -> rowptr (shuffle scan, 2 barriers)
// ---------------------------------------------------------------------------
__global__ __launch_bounds__(1024) void scan_kernel(
    const int* __restrict__ deg, int* __restrict__ rowptr, int N)
{
    __shared__ int tot[NMAX];
    __shared__ int wsum[16];
    const int tid = threadIdx.x;
    const int lane = tid & 63;
    const int wid = tid >> 6;

    for (int d = tid; d < N; d += 1024) tot[d] = deg[d];
    __syncthreads();

    const int CH = (N + 1023) / 1024;
    const int b = tid * CH;
    const int e = min(b + CH, N);
    int s = 0;
    for (int i = b; i < e; ++i) s += tot[i];

    // wave-level inclusive scan of chunk sums
    int incl = s;
    #pragma unroll
    for (int off = 1; off < 64; off <<= 1) {
        int t = __shfl_up(incl, off);
        if (lane >= off) incl += t;
    }
    if (lane == 63) wsum[wid] = incl;
    __syncthreads();
    if (wid == 0) {
        int v = (lane < 16) ? wsum[lane] : 0;
        #pragma unroll
        for (int off = 1; off < 16; off <<= 1) {
            int t = __shfl_up(v, off);
            if (lane >= off) v += t;
        }
        if (lane < 16) wsum[lane] = v;
    }
    __syncthreads();
    const int wbase = (wid > 0) ? wsum[wid - 1] : 0;
    int run = wbase + incl - s;           // exclusive base of this chunk
    for (int i = b; i < e; ++i) {
        const int t = tot[i];
        rowptr[i] = run;
        run += t;
    }
    if (tid == 1023) rowptr[N] = wsum[15];
}

// ---------------------------------------------------------------------------
// K2c: bh counts -> per-partition exclusive bases, in place.
// ---------------------------------------------------------------------------
__global__ __launch_bounds__(256) void base_kernel(
    int* __restrict__ bh, const int* __restrict__ rowptr, int N)
{
    const int d = blockIdx.x * 256 + threadIdx.x;
    if (d < N) {
        int c = rowptr[d];
        #pragma unroll
        for (int p = 0; p < NP; ++p) {
            const int cnt = bh[p * N + d];
            bh[p * N + d] = c;
            c += cnt;
        }
    }
}

// ---------------------------------------------------------------------------
// K3: scatter src ids into CSR slots (LDS cursors).
// ---------------------------------------------------------------------------
__global__ __launch_bounds__(256) void scatter_kernel(
    const int* __restrict__ src, const int* __restrict__ dst,
    const int* __restrict__ base, int* __restrict__ ssrc,
    int N, int E, int C)
{
    __shared__ int cur[NMAX];
    const int p = blockIdx.x, tid = threadIdx.x;
    for (int d = tid; d < N; d += 256) cur[d] = base[p * N + d];
    __syncthreads();

    const int lo = p * C;
    const int hi = min(lo + C, E);
    const int n = hi - lo;
    if (n <= 0) return;

    if (((lo | E) & 3) == 0) {
        const int4* s4 = (const int4*)(src + lo);
        const int4* d4 = (const int4*)(dst + lo);
        const int n4 = n >> 2;
        for (int i = tid; i < n4; i += 256) {
            int4 s = s4[i];
            int4 d = d4[i];
            int p0 = atomicAdd(&cur[d.x], 1); ssrc[p0] = s.x;
            int p1 = atomicAdd(&cur[d.y], 1); ssrc[p1] = s.y;
            int p2 = atomicAdd(&cur[d.z], 1); ssrc[p2] = s.z;
            int p3 = atomicAdd(&cur[d.w], 1); ssrc[p3] = s.w;
        }
        for (int i = lo + (n4 << 2) + tid; i < hi; i += 256) {
            int pos = atomicAdd(&cur[dst[i]], 1); ssrc[pos] = src[i];
        }
    } else {
        for (int i = lo + tid; i < hi; i += 256) {
            int pos = atomicAdd(&cur[dst[i]], 1); ssrc[pos] = src[i];
        }
    }
}

// ---------------------------------------------------------------------------
// K4: quarter-wave (16 lanes) per node; lane owns 8 dims (uint4 bf16 loads).
// Head = 4-lane group (dot reduce = xor 1,2). 4-edge batches, pipelined
// gathers + two-deep index prefetch. Residual + LayerNorm fused.
// ---------------------------------------------------------------------------
__global__ __launch_bounds__(256) void agg_kernel(
    const unsigned short* __restrict__ Qu, const unsigned short* __restrict__ KVu,
    const float* __restrict__ Rb,
    const int* __restrict__ rowptr, const int* __restrict__ ssrc,
    const float* __restrict__ gamma, const float* __restrict__ beta,
    float* __restrict__ out, int N)
{
    const int wave = threadIdx.x >> 6;
    const int lane = threadIdx.x & 63;
    const int qtr = lane >> 4;
    const int lq = lane & 15;
    const int n = blockIdx.x * 16 + wave * 4 + qtr;
    if (n >= N) return;
    const int d0 = lq * 8;

    // unpack q (8 bf16)
    const uint4 qu = *reinterpret_cast<const uint4*>(&Qu[(size_t)n * 128 + d0]);
    const float qf0 = __uint_as_float(qu.x << 16), qf1 = __uint_as_float(qu.x & 0xFFFF0000u);
    const float qf2 = __uint_as_float(qu.y << 16), qf3 = __uint_as_float(qu.y & 0xFFFF0000u);
    const float qf4 = __uint_as_float(qu.z << 16), qf5 = __uint_as_float(qu.z & 0xFFFF0000u);
    const float qf6 = __uint_as_float(qu.w << 16), qf7 = __uint_as_float(qu.w & 0xFFFF0000u);

    const int beg = rowptr[n];
    const int end = rowptr[n + 1];

    float4 A0a = make_float4(0.f, 0.f, 0.f, 0.f), A0b = A0a;
    float4 A1a = A0a, A1b = A0a, A2a = A0a, A2b = A0a, A3a = A0a, A3b = A0a;
    float L0 = 0.f, L1 = 0.f, L2 = 0.f, L3 = 0.f;

#define GATHER(S, NK, NV)                                                     \
    {                                                                         \
        const unsigned short* bp = &KVu[(size_t)(S) * 256 + d0];              \
        NK = *reinterpret_cast<const uint4*>(bp);                             \
        NV = *reinterpret_cast<const uint4*>(bp + 128);                       \
    }
#define STEP(KU, VU, Aa, Ab, L)                                               \
    {                                                                         \
        const float k0 = __uint_as_float((KU).x << 16), k1 = __uint_as_float((KU).x & 0xFFFF0000u); \
        const float k2 = __uint_as_float((KU).y << 16), k3 = __uint_as_float((KU).y & 0xFFFF0000u); \
        const float k4 = __uint_as_float((KU).z << 16), k5 = __uint_as_float((KU).z & 0xFFFF0000u); \
        const float k6 = __uint_as_float((KU).w << 16), k7 = __uint_as_float((KU).w & 0xFFFF0000u); \
        float p = qf0 * k0 + qf1 * k1 + qf2 * k2 + qf3 * k3                   \
                + qf4 * k4 + qf5 * k5 + qf6 * k6 + qf7 * k7;                  \
        p += __shfl_xor(p, 1);                                                \
        p += __shfl_xor(p, 2);                                                \
        const float e1 = exp2f(p * SC2);                                      \
        const float v0 = __uint_as_float((VU).x << 16), v1 = __uint_as_float((VU).x & 0xFFFF0000u); \
        const float v2 = __uint_as_float((VU).y << 16), v3 = __uint_as_float((VU).y & 0xFFFF0000u); \
        const float v4 = __uint_as_float((VU).z << 16), v5 = __uint_as_float((VU).z & 0xFFFF0000u); \
        const float v6 = __uint_as_float((VU).w << 16), v7 = __uint_as_float((VU).w & 0xFFFF0000u); \
        Aa.x += e1 * v0; Aa.y += e1 * v1; Aa.z += e1 * v2; Aa.w += e1 * v3;   \
        Ab.x += e1 * v4; Ab.y += e1 * v5; Ab.z += e1 * v6; Ab.w += e1 * v7;   \
        L += e1;                                                              \
    }

    uint4 nk0, nv0, nk1, nv1, nk2, nv2, nk3, nv3;
    int j = beg;
    const int nb = (end - beg) >> 2;
    if (nb > 0) {
        int c0i = ssrc[j], c1i = ssrc[j + 1], c2i = ssrc[j + 2], c3i = ssrc[j + 3];
        GATHER(c0i, nk0, nv0); GATHER(c1i, nk1, nv1);
        GATHER(c2i, nk2, nv2); GATHER(c3i, nk3, nv3);
        // prefetch next indices (ssrc padded by 8 -> safe)
        int x0 = ssrc[j + 4], x1 = ssrc[j + 5], x2 = ssrc[j + 6], x3 = ssrc[j + 7];
        for (int bi = 1; bi < nb; ++bi) {
            const uint4 ck0 = nk0, cv0 = nv0, ck1 = nk1, cv1 = nv1;
            const uint4 ck2 = nk2, cv2 = nv2, ck3 = nk3, cv3 = nv3;
            c0i = x0; c1i = x1; c2i = x2; c3i = x3;
            const int nbase = j + (bi + 1) * 4;           // prefetch (padded)
            x0 = ssrc[nbase]; x1 = ssrc[nbase + 1];
            x2 = ssrc[nbase + 2]; x3 = ssrc[nbase + 3];
            GATHER(c0i, nk0, nv0); GATHER(c1i, nk1, nv1);
            GATHER(c2i, nk2, nv2); GATHER(c3i, nk3, nv3);
            STEP(ck0, cv0, A0a, A0b, L0);
            STEP(ck1, cv1, A1a, A1b, L1);
            STEP(ck2, cv2, A2a, A2b, L2);
            STEP(ck3, cv3, A3a, A3b, L3);
        }
        STEP(nk0, nv0, A0a, A0b, L0);
        STEP(nk1, nv1, A1a, A1b, L1);
        STEP(nk2, nv2, A2a, A2b, L2);
        STEP(nk3, nv3, A3a, A3b, L3);
        j = beg + nb * 4;
    }
    for (; j < end; ++j) {
        const int s0 = ssrc[j];
        uint4 k0u, v0u;
        GATHER(s0, k0u, v0u);
        STEP(k0u, v0u, A0a, A0b, L0);
    }
#undef GATHER
#undef STEP

    const float L = (L0 + L1) + (L2 + L3);
    const float inv = 1.f / (L + 1e-12f);          // empty segment -> x = r
    const float4 ra = *reinterpret_cast<const float4*>(&Rb[(size_t)n * 128 + d0]);
    const float4 rb = *reinterpret_cast<const float4*>(&Rb[(size_t)n * 128 + d0 + 4]);
    float xa0 = ((A0a.x + A1a.x) + (A2a.x + A3a.x)) * inv + ra.x;
    float xa1 = ((A0a.y + A1a.y) + (A2a.y + A3a.y)) * inv + ra.y;
    float xa2 = ((A0a.z + A1a.z) + (A2a.z + A3a.z)) * inv + ra.z;
    float xa3 = ((A0a.w + A1a.w) + (A2a.w + A3a.w)) * inv + ra.w;
    float xb0 = ((A0b.x + A1b.x) + (A2b.x + A3b.x)) * inv + rb.x;
    float xb1 = ((A0b.y + A1b.y) + (A2b.y + A3b.y)) * inv + rb.y;
    float xb2 = ((A0b.z + A1b.z) + (A2b.z + A3b.z)) * inv + rb.z;
    float xb3 = ((A0b.w + A1b.w) + (A2b.w + A3b.w)) * inv + rb.w;

    // LayerNorm over 16 lanes x 8 dims
    float s1v = (xa0 + xa1 + xa2 + xa3) + (xb0 + xb1 + xb2 + xb3);
    float s2v = xa0 * xa0 + xa1 * xa1 + xa2 * xa2 + xa3 * xa3
              + xb0 * xb0 + xb1 * xb1 + xb2 * xb2 + xb3 * xb3;
    #pragma unroll
    for (int off = 8; off; off >>= 1) {
        s1v += __shfl_xor(s1v, off);
        s2v += __shfl_xor(s2v, off);
    }
    const float mu = s1v * (1.f / 128.f);
    float var = s2v * (1.f / 128.f) - mu * mu;
    var = fmaxf(var, 0.f);
    const float rs = rsqrtf(var + LN_EPS);

    const float4 ga = *reinterpret_cast<const float4*>(&gamma[d0]);
    const float4 gb = *reinterpret_cast<const float4*>(&gamma[d0 + 4]);
    const float4 ba = *reinterpret_cast<const float4*>(&beta[d0]);
    const float4 bb = *reinterpret_cast<const float4*>(&beta[d0 + 4]);
    float4 oa, ob;
    oa.x = ga.x * (xa0 - mu) * rs + ba.x;
    oa.y = ga.y * (xa1 - mu) * rs + ba.y;
    oa.z = ga.z * (xa2 - mu) * rs + ba.z;
    oa.w = ga.w * (xa3 - mu) * rs + ba.w;
    ob.x = gb.x * (xb0 - mu) * rs + bb.x;
    ob.y = gb.y * (xb1 - mu) * rs + bb.y;
    ob.z = gb.z * (xb2 - mu) * rs + bb.z;
    ob.w = gb.w * (xb3 - mu) * rs + bb.w;
    *reinterpret_cast<float4*>(&out[(size_t)n * 128 + d0]) = oa;
    *reinterpret_cast<float4*>(&out[(size_t)n * 128 + d0 + 4]) = ob;
}

// ---------------------------------------------------------------------------
extern "C" void kernel_launch(void* const* d_in, const int* in_sizes, int n_in,
                              void* d_out, int out_size, void* d_ws, size_t ws_size,
                              hipStream_t stream)
{
    const float* nodes = (const float*)d_in[0];
    const float* W_Q   = (const float*)d_in[1];
    const float* W_K   = (const float*)d_in[2];
    const float* W_V   = (const float*)d_in[3];
    const float* W_res = (const float*)d_in[4];
    const float* b_res = (const float*)d_in[5];
    const float* gamma = (const float*)d_in[6];
    const float* beta  = (const float*)d_in[7];
    const int*   eidx  = (const int*)d_in[8];

    const int N = in_sizes[0] / FDIM;
    const int E = in_sizes[8] / 2;
    const int* src = eidx;
    const int* dst = eidx + E;

    float* out = (float*)d_out;

    // workspace carve
    unsigned short* KVu = (unsigned short*)d_ws;              // N*256 bf16
    unsigned short* Qu  = KVu + (size_t)N * 256;              // N*128 bf16
    unsigned short* Wt  = Qu + (size_t)N * 128;               // 4*128*128 bf16
    float* Rb   = (float*)(Wt + 4 * 16384);                   // N*128 f32
    int* bh     = (int*)(Rb + (size_t)N * 128);               // NP*N (counts -> bases)
    int* rowptr = bh + (size_t)NP * N;                        // N+1
    int* deg    = rowptr + (N + 1);                           // N
    int* ssrc   = deg + N;                                    // E + 8 (pad for prefetch)

    const int C = (((E + NP - 1) / NP) + 3) & ~3;             // chunk, mult of 4
    const int nG = (N + 63) / 64;
    const int nB = (N + 255) / 256;

    prep_kernel<<<16, 256, 0, stream>>>(W_Q, W_K, W_V, W_res, Wt);

    dim3 ggrid(nG, 5);                                        // y==0 -> histogram
    gemm_hist_kernel<<<ggrid, 256, 0, stream>>>(nodes, Wt, b_res,
                                                Qu, KVu, Rb, N, dst, bh, E, C);
    deg_kernel<<<nB, 256, 0, stream>>>(bh, deg, N);
    scan_kernel<<<1, 1024, 0, stream>>>(deg, rowptr, N);
    base_kernel<<<nB, 256, 0, stream>>>(bh, rowptr, N);
    scatter_kernel<<<NP, 256, 0, stream>>>(src, dst, bh, ssrc, N, E, C);
    agg_kernel<<<(N + 15) / 16, 256, 0, stream>>>(Qu, KVu, Rb, rowptr, ssrc,
                                                  gamma, beta, out, N);
}

// Round 14
// 88.521 us; speedup vs baseline: 1.3232x; 1.0764x over previous
//
#include <hip/hip_runtime.h>
#include <math.h>

#define FDIM 128
#define NP 64                 // CSR partition blocks
#define NMAX 10240            // LDS capacity (N=10000)
static constexpr float SC2 = 0.17677669529663687f * 1.4426950408889634f; // (1/sqrt(32))*log2(e)
static constexpr float LN_EPS = 1e-5f;

typedef __attribute__((ext_vector_type(8))) short bf16x8;
typedef __attribute__((ext_vector_type(4))) float f32x4;

__device__ __forceinline__ unsigned short f2bf(float f) {
    unsigned u = __float_as_uint(f);
    unsigned r = u + 0x7FFFu + ((u >> 16) & 1u);   // RNE
    return (unsigned short)(r >> 16);
}

// ---------------------------------------------------------------------------
// K0: prep — W_{Q,K,V,res} f32 -> W^T bf16 (Wt[wi][c][k]). 16 blocks.
// ---------------------------------------------------------------------------
__global__ __launch_bounds__(256) void prep_kernel(
    const float* __restrict__ Wq, const float* __restrict__ Wk,
    const float* __restrict__ Wv, const float* __restrict__ Wr,
    unsigned short* __restrict__ Wt)
{
    const int tid = threadIdx.x;
    const int t = blockIdx.x;           // 0..15
    const int wiW = t >> 2, q = t & 3;
    const float* __restrict__ W = (wiW == 0) ? Wq : (wiW == 1) ? Wk : (wiW == 2) ? Wv : Wr;
    const int c = q * 32 + (tid >> 3);  // 0..127
    const int k0 = (tid & 7) * 16;
    unsigned short* dp = &Wt[(size_t)wiW * 16384 + c * 128 + k0];
    #pragma unroll
    for (int kk = 0; kk < 16; ++kk)
        dp[kk] = f2bf(W[(k0 + kk) * FDIM + c]);
}

// ---------------------------------------------------------------------------
// K1: fused MFMA GEMM (blockIdx.y 1..4) + LDS histogram + rank (y==0, x<NP).
// Hist: bh[p*N+d] counts AND rank[e] = within-(p,d) arrival index (the LDS
// atomicAdd return), enabling a fully parallel cursor-free scatter.
// ---------------------------------------------------------------------------
__global__ __launch_bounds__(256) void gemm_hist_kernel(
    const float* __restrict__ nodes,
    const unsigned short* __restrict__ Wt,
    const float* __restrict__ br,
    unsigned short* __restrict__ Qu, unsigned short* __restrict__ KVu,
    float* __restrict__ Rb, int N,
    const int* __restrict__ dst, int* __restrict__ bh,
    int* __restrict__ rank, int E, int C)
{
    __shared__ __align__(16) char smem[52224];   // max(hist 40960, 17408+34816)
    const int tid = threadIdx.x;
    const int wi = blockIdx.y;

    if (wi == 0) {                    // ---- histogram partition ----
        const int p = blockIdx.x;
        if (p >= NP) return;
        int* h = (int*)smem;
        for (int i = tid; i < N; i += 256) h[i] = 0;
        __syncthreads();
        const int lo = p * C;
        const int hi = min(lo + C, E);
        const int n = hi - lo;
        if (n > 0) {
            if (((lo | E) & 3) == 0) {
                const int4* d4 = (const int4*)(dst + lo);
                int4* r4p = (int4*)(rank + lo);
                const int n4 = n >> 2;
                for (int i = tid; i < n4; i += 256) {
                    int4 d = d4[i];
                    int4 r;
                    r.x = atomicAdd(&h[d.x], 1);
                    r.y = atomicAdd(&h[d.y], 1);
                    r.z = atomicAdd(&h[d.z], 1);
                    r.w = atomicAdd(&h[d.w], 1);
                    r4p[i] = r;
                }
                for (int i = lo + (n4 << 2) + tid; i < hi; i += 256)
                    rank[i] = atomicAdd(&h[dst[i]], 1);
            } else {
                for (int i = lo + tid; i < hi; i += 256)
                    rank[i] = atomicAdd(&h[dst[i]], 1);
            }
        }
        __syncthreads();
        for (int i = tid; i < N; i += 256) bh[p * N + i] = h[i];
        return;
    }

    // ---- GEMM partition ----
    const int gw = wi - 1;            // 0=Q, 1=K, 2=V, 3=R
    const int row0 = blockIdx.x * 64;
    unsigned short (*As)[136] = (unsigned short(*)[136])smem;            // 64 rows
    unsigned short (*Ws)[136] = (unsigned short(*)[136])(smem + 64 * 272);// 128 rows

    // stage As: 64 rows x 128 cols, f32 -> bf16 inline
    #pragma unroll
    for (int i = 0; i < 8; ++i) {
        const int idx = tid + i * 256;           // 0..2047 float4s
        const int r = idx >> 5, c4 = idx & 31;
        const int gr = row0 + r;
        float4 v = make_float4(0.f, 0.f, 0.f, 0.f);
        if (gr < N) v = *reinterpret_cast<const float4*>(&nodes[(size_t)gr * FDIM + c4 * 4]);
        ushort4 o;
        o.x = f2bf(v.x); o.y = f2bf(v.y); o.z = f2bf(v.z); o.w = f2bf(v.w);
        *reinterpret_cast<ushort4*>(&As[r][c4 * 4]) = o;
    }
    // stage W^T: 128 rows x 16 chunks of 16B (already bf16)
    const unsigned short* Wg = &Wt[(size_t)gw * 16384];
    #pragma unroll
    for (int i = 0; i < 8; ++i) {
        const int idx = tid + i * 256;           // 0..2047
        const int r = idx >> 4, ch = idx & 15;
        const uint4 v = *reinterpret_cast<const uint4*>(&Wg[r * 128 + ch * 8]);
        *reinterpret_cast<uint4*>(&Ws[r][ch * 8]) = v;
    }
    __syncthreads();

    const int w = tid >> 6;           // wave 0..3 -> rows w*16..
    const int l = tid & 63;
    const int lr = l & 15;
    const int lh = l >> 4;

    f32x4 acc[8];
    #pragma unroll
    for (int ct = 0; ct < 8; ++ct) acc[ct] = (f32x4){0.f, 0.f, 0.f, 0.f};

    #pragma unroll
    for (int kc = 0; kc < 4; ++kc) {
        const bf16x8 a = *reinterpret_cast<const bf16x8*>(&As[w * 16 + lr][kc * 32 + lh * 8]);
        #pragma unroll
        for (int ct = 0; ct < 8; ++ct) {
            const bf16x8 bb = *reinterpret_cast<const bf16x8*>(&Ws[ct * 16 + lr][kc * 32 + lh * 8]);
            acc[ct] = __builtin_amdgcn_mfma_f32_16x16x32_bf16(a, bb, acc[ct], 0, 0, 0);
        }
    }

    // epilogue: col = ct*16 + lr, row = row0 + w*16 + lh*4 + r
    const int rbase = row0 + w * 16 + lh * 4;
    #pragma unroll
    for (int ct = 0; ct < 8; ++ct) {
        const int col = ct * 16 + lr;
        float bc = 0.f;
        if (gw == 3) bc = br[col];
        #pragma unroll
        for (int r = 0; r < 4; ++r) {
            const int row = rbase + r;
            if (row >= N) continue;
            const float val = acc[ct][r];
            if (gw == 0)      Qu[(size_t)row * 128 + col] = f2bf(val);
            else if (gw == 1) KVu[(size_t)row * 256 + col] = f2bf(val);
            else if (gw == 2) KVu[(size_t)row * 256 + 128 + col] = f2bf(val);
            else              Rb[(size_t)row * 128 + col] = val + bc;
        }
    }
}

// ---------------------------------------------------------------------------
// K2a: deg[d] = sum_p bh[p][d]
// ---------------------------------------------------------------------------
__global__ __launch_bounds__(256) void deg_kernel(
    const int* __restrict__ bh, int* __restrict__ deg, int N)
{
    const int d = blockIdx.x * 256 + threadIdx.x;
    if (d < N) {
        int s = 0;
        #pragma unroll
        for (int p = 0; p < NP; ++p) s += bh[p * N + d];
        deg[d] = s;
    }
}

// ---------------------------------------------------------------------------
// K2b: single-block exclusive scan of deg -> rowptr (shuffle scan, 2 barriers)
// ---------------------------------------------------------------------------
__global__ __launch_bounds__(1024) void scan_kernel(
    const int* __restrict__ deg, int* __restrict__ rowptr, int N)
{
    __shared__ int tot[NMAX];
    __shared__ int wsum[16];
    const int tid = threadIdx.x;
    const int lane = tid & 63;
    const int wid = tid >> 6;

    for (int d = tid; d < N; d += 1024) tot[d] = deg[d];
    __syncthreads();

    const int CH = (N + 1023) / 1024;
    const int b = tid * CH;
    const int e = min(b + CH, N);
    int s = 0;
    for (int i = b; i < e; ++i) s += tot[i];

    int incl = s;
    #pragma unroll
    for (int off = 1; off < 64; off <<= 1) {
        int t = __shfl_up(incl, off);
        if (lane >= off) incl += t;
    }
    if (lane == 63) wsum[wid] = incl;
    __syncthreads();
    if (wid == 0) {
        int v = (lane < 16) ? wsum[lane] : 0;
        #pragma unroll
        for (int off = 1; off < 16; off <<= 1) {
            int t = __shfl_up(v, off);
            if (lane >= off) v += t;
        }
        if (lane < 16) wsum[lane] = v;
    }
    __syncthreads();
    const int wbase = (wid > 0) ? wsum[wid - 1] : 0;
    int run = wbase + incl - s;
    for (int i = b; i < e; ++i) {
        const int t = tot[i];
        rowptr[i] = run;
        run += t;
    }
    if (tid == 1023) rowptr[N] = wsum[15];
}

// ---------------------------------------------------------------------------
// K2c: bh counts -> per-partition exclusive bases, in place.
// ---------------------------------------------------------------------------
__global__ __launch_bounds__(256) void base_kernel(
    int* __restrict__ bh, const int* __restrict__ rowptr, int N)
{
    const int d = blockIdx.x * 256 + threadIdx.x;
    if (d < N) {
        int c = rowptr[d];
        #pragma unroll
        for (int p = 0; p < NP; ++p) {
            const int cnt = bh[p * N + d];
            bh[p * N + d] = c;
            c += cnt;
        }
    }
}

// ---------------------------------------------------------------------------
// K3: cursor-free scatter: ssrc[base[p][d] + rank[e]] = src[e].
// 8 sub-blocks per partition (p = blockIdx.x>>3); no LDS, no atomics.
// ---------------------------------------------------------------------------
__global__ __launch_bounds__(256) void scatter_kernel(
    const int* __restrict__ src, const int* __restrict__ dst,
    const int* __restrict__ rank, const int* __restrict__ base,
    int* __restrict__ ssrc, int N, int E, int C)
{
    const int p = blockIdx.x >> 3;
    const int sub = blockIdx.x & 7;
    const int CS = C >> 3;                       // C mult of 32 -> CS mult of 4
    const int lo = p * C + sub * CS;
    const int hi = min(lo + CS, E);
    const int n = hi - lo;
    if (n <= 0) return;
    const int* bp = &base[p * N];

    if (((lo | E) & 3) == 0) {
        const int4* s4 = (const int4*)(src + lo);
        const int4* d4 = (const int4*)(dst + lo);
        const int4* r4 = (const int4*)(rank + lo);
        const int n4 = n >> 2;
        for (int i = threadIdx.x; i < n4; i += 256) {
            const int4 s = s4[i];
            const int4 d = d4[i];
            const int4 r = r4[i];
            ssrc[bp[d.x] + r.x] = s.x;
            ssrc[bp[d.y] + r.y] = s.y;
            ssrc[bp[d.z] + r.z] = s.z;
            ssrc[bp[d.w] + r.w] = s.w;
        }
        for (int i = lo + (n4 << 2) + threadIdx.x; i < hi; i += 256)
            ssrc[bp[dst[i]] + rank[i]] = src[i];
    } else {
        for (int i = lo + threadIdx.x; i < hi; i += 256)
            ssrc[bp[dst[i]] + rank[i]] = src[i];
    }
}

// ---------------------------------------------------------------------------
// K4: quarter-wave (16 lanes) per node; lane owns 8 dims (uint4 bf16 loads).
// Head = 4-lane group (dot reduce = xor 1,2). 4-edge batches, pipelined
// gathers + two-deep index prefetch. Residual + LayerNorm fused.
// ---------------------------------------------------------------------------
__global__ __launch_bounds__(256) void agg_kernel(
    const unsigned short* __restrict__ Qu, const unsigned short* __restrict__ KVu,
    const float* __restrict__ Rb,
    const int* __restrict__ rowptr, const int* __restrict__ ssrc,
    const float* __restrict__ gamma, const float* __restrict__ beta,
    float* __restrict__ out, int N)
{
    const int wave = threadIdx.x >> 6;
    const int lane = threadIdx.x & 63;
    const int qtr = lane >> 4;
    const int lq = lane & 15;
    const int n = blockIdx.x * 16 + wave * 4 + qtr;
    if (n >= N) return;
    const int d0 = lq * 8;

    const uint4 qu = *reinterpret_cast<const uint4*>(&Qu[(size_t)n * 128 + d0]);
    const float qf0 = __uint_as_float(qu.x << 16), qf1 = __uint_as_float(qu.x & 0xFFFF0000u);
    const float qf2 = __uint_as_float(qu.y << 16), qf3 = __uint_as_float(qu.y & 0xFFFF0000u);
    const float qf4 = __uint_as_float(qu.z << 16), qf5 = __uint_as_float(qu.z & 0xFFFF0000u);
    const float qf6 = __uint_as_float(qu.w << 16), qf7 = __uint_as_float(qu.w & 0xFFFF0000u);

    const int beg = rowptr[n];
    const int end = rowptr[n + 1];

    float4 A0a = make_float4(0.f, 0.f, 0.f, 0.f), A0b = A0a;
    float4 A1a = A0a, A1b = A0a, A2a = A0a, A2b = A0a, A3a = A0a, A3b = A0a;
    float L0 = 0.f, L1 = 0.f, L2 = 0.f, L3 = 0.f;

#define GATHER(S, NK, NV)                                                     \
    {                                                                         \
        const unsigned short* bp = &KVu[(size_t)(S) * 256 + d0];              \
        NK = *reinterpret_cast<const uint4*>(bp);                             \
        NV = *reinterpret_cast<const uint4*>(bp + 128);                       \
    }
#define STEP(KU, VU, Aa, Ab, L)                                               \
    {                                                                         \
        const float k0 = __uint_as_float((KU).x << 16), k1 = __uint_as_float((KU).x & 0xFFFF0000u); \
        const float k2 = __uint_as_float((KU).y << 16), k3 = __uint_as_float((KU).y & 0xFFFF0000u); \
        const float k4 = __uint_as_float((KU).z << 16), k5 = __uint_as_float((KU).z & 0xFFFF0000u); \
        const float k6 = __uint_as_float((KU).w << 16), k7 = __uint_as_float((KU).w & 0xFFFF0000u); \
        float p = qf0 * k0 + qf1 * k1 + qf2 * k2 + qf3 * k3                   \
                + qf4 * k4 + qf5 * k5 + qf6 * k6 + qf7 * k7;                  \
        p += __shfl_xor(p, 1);                                                \
        p += __shfl_xor(p, 2);                                                \
        const float e1 = exp2f(p * SC2);                                      \
        const float v0 = __uint_as_float((VU).x << 16), v1 = __uint_as_float((VU).x & 0xFFFF0000u); \
        const float v2 = __uint_as_float((VU).y << 16), v3 = __uint_as_float((VU).y & 0xFFFF0000u); \
        const float v4 = __uint_as_float((VU).z << 16), v5 = __uint_as_float((VU).z & 0xFFFF0000u); \
        const float v6 = __uint_as_float((VU).w << 16), v7 = __uint_as_float((VU).w & 0xFFFF0000u); \
        Aa.x += e1 * v0; Aa.y += e1 * v1; Aa.z += e1 * v2; Aa.w += e1 * v3;   \
        Ab.x += e1 * v4; Ab.y += e1 * v5; Ab.z += e1 * v6; Ab.w += e1 * v7;   \
        L += e1;                                                              \
    }

    uint4 nk0, nv0, nk1, nv1, nk2, nv2, nk3, nv3;
    int j = beg;
    const int nb = (end - beg) >> 2;
    if (nb > 0) {
        int c0i = ssrc[j], c1i = ssrc[j + 1], c2i = ssrc[j + 2], c3i = ssrc[j + 3];
        GATHER(c0i, nk0, nv0); GATHER(c1i, nk1, nv1);
        GATHER(c2i, nk2, nv2); GATHER(c3i, nk3, nv3);
        int x0 = ssrc[j + 4], x1 = ssrc[j + 5], x2 = ssrc[j + 6], x3 = ssrc[j + 7];
        for (int bi = 1; bi < nb; ++bi) {
            const uint4 ck0 = nk0, cv0 = nv0, ck1 = nk1, cv1 = nv1;
            const uint4 ck2 = nk2, cv2 = nv2, ck3 = nk3, cv3 = nv3;
            c0i = x0; c1i = x1; c2i = x2; c3i = x3;
            const int nbase = j + (bi + 1) * 4;
            x0 = ssrc[nbase]; x1 = ssrc[nbase + 1];
            x2 = ssrc[nbase + 2]; x3 = ssrc[nbase + 3];
            GATHER(c0i, nk0, nv0); GATHER(c1i, nk1, nv1);
            GATHER(c2i, nk2, nv2); GATHER(c3i, nk3, nv3);
            STEP(ck0, cv0, A0a, A0b, L0);
            STEP(ck1, cv1, A1a, A1b, L1);
            STEP(ck2, cv2, A2a, A2b, L2);
            STEP(ck3, cv3, A3a, A3b, L3);
        }
        STEP(nk0, nv0, A0a, A0b, L0);
        STEP(nk1, nv1, A1a, A1b, L1);
        STEP(nk2, nv2, A2a, A2b, L2);
        STEP(nk3, nv3, A3a, A3b, L3);
        j = beg + nb * 4;
    }
    for (; j < end; ++j) {
        const int s0 = ssrc[j];
        uint4 k0u, v0u;
        GATHER(s0, k0u, v0u);
        STEP(k0u, v0u, A0a, A0b, L0);
    }
#undef GATHER
#undef STEP

    const float L = (L0 + L1) + (L2 + L3);
    const float inv = 1.f / (L + 1e-12f);
    const float4 ra = *reinterpret_cast<const float4*>(&Rb[(size_t)n * 128 + d0]);
    const float4 rb = *reinterpret_cast<const float4*>(&Rb[(size_t)n * 128 + d0 + 4]);
    float xa0 = ((A0a.x + A1a.x) + (A2a.x + A3a.x)) * inv + ra.x;
    float xa1 = ((A0a.y + A1a.y) + (A2a.y + A3a.y)) * inv + ra.y;
    float xa2 = ((A0a.z + A1a.z) + (A2a.z + A3a.z)) * inv + ra.z;
    float xa3 = ((A0a.w + A1a.w) + (A2a.w + A3a.w)) * inv + ra.w;
    float xb0 = ((A0b.x + A1b.x) + (A2b.x + A3b.x)) * inv + rb.x;
    float xb1 = ((A0b.y + A1b.y) + (A2b.y + A3b.y)) * inv + rb.y;
    float xb2 = ((A0b.z + A1b.z) + (A2b.z + A3b.z)) * inv + rb.z;
    float xb3 = ((A0b.w + A1b.w) + (A2b.w + A3b.w)) * inv + rb.w;

    float s1v = (xa0 + xa1 + xa2 + xa3) + (xb0 + xb1 + xb2 + xb3);
    float s2v = xa0 * xa0 + xa1 * xa1 + xa2 * xa2 + xa3 * xa3
              + xb0 * xb0 + xb1 * xb1 + xb2 * xb2 + xb3 * xb3;
    #pragma unroll
    for (int off = 8; off; off >>= 1) {
        s1v += __shfl_xor(s1v, off);
        s2v += __shfl_xor(s2v, off);
    }
    const float mu = s1v * (1.f / 128.f);
    float var = s2v * (1.f / 128.f) - mu * mu;
    var = fmaxf(var, 0.f);
    const float rs = rsqrtf(var + LN_EPS);

    const float4 ga = *reinterpret_cast<const float4*>(&gamma[d0]);
    const float4 gb = *reinterpret_cast<const float4*>(&gamma[d0 + 4]);
    const float4 ba = *reinterpret_cast<const float4*>(&beta[d0]);
    const float4 bb = *reinterpret_cast<const float4*>(&beta[d0 + 4]);
    float4 oa, ob;
    oa.x = ga.x * (xa0 - mu) * rs + ba.x;
    oa.y = ga.y * (xa1 - mu) * rs + ba.y;
    oa.z = ga.z * (xa2 - mu) * rs + ba.z;
    oa.w = ga.w * (xa3 - mu) * rs + ba.w;
    ob.x = gb.x * (xb0 - mu) * rs + bb.x;
    ob.y = gb.y * (xb1 - mu) * rs + bb.y;
    ob.z = gb.z * (xb2 - mu) * rs + bb.z;
    ob.w = gb.w * (xb3 - mu) * rs + bb.w;
    *reinterpret_cast<float4*>(&out[(size_t)n * 128 + d0]) = oa;
    *reinterpret_cast<float4*>(&out[(size_t)n * 128 + d0 + 4]) = ob;
}

// ---------------------------------------------------------------------------
extern "C" void kernel_launch(void* const* d_in, const int* in_sizes, int n_in,
                              void* d_out, int out_size, void* d_ws, size_t ws_size,
                              hipStream_t stream)
{
    const float* nodes = (const float*)d_in[0];
    const float* W_Q   = (const float*)d_in[1];
    const float* W_K   = (const float*)d_in[2];
    const float* W_V   = (const float*)d_in[3];
    const float* W_res = (const float*)d_in[4];
    const float* b_res = (const float*)d_in[5];
    const float* gamma = (const float*)d_in[6];
    const float* beta  = (const float*)d_in[7];
    const int*   eidx  = (const int*)d_in[8];

    const int N = in_sizes[0] / FDIM;
    const int E = in_sizes[8] / 2;
    const int* src = eidx;
    const int* dst = eidx + E;

    float* out = (float*)d_out;

    // workspace carve
    unsigned short* KVu = (unsigned short*)d_ws;              // N*256 bf16
    unsigned short* Qu  = KVu + (size_t)N * 256;              // N*128 bf16
    unsigned short* Wt  = Qu + (size_t)N * 128;               // 4*128*128 bf16
    float* Rb   = (float*)(Wt + 4 * 16384);                   // N*128 f32
    int* bh     = (int*)(Rb + (size_t)N * 128);               // NP*N (counts -> bases)
    int* rowptr = bh + (size_t)NP * N;                        // N+1
    int* deg    = rowptr + (N + 1);                           // N
    int* rank   = deg + N;                                    // E
    int* ssrc   = rank + E;                                   // E + 8 (pad for prefetch)

    const int C = (((E + NP - 1) / NP) + 31) & ~31;           // chunk, mult of 32
    const int nG = (N + 63) / 64;
    const int nB = (N + 255) / 256;

    prep_kernel<<<16, 256, 0, stream>>>(W_Q, W_K, W_V, W_res, Wt);

    dim3 ggrid(nG, 5);                                        // y==0 -> histogram
    gemm_hist_kernel<<<ggrid, 256, 0, stream>>>(nodes, Wt, b_res,
                                                Qu, KVu, Rb, N, dst, bh, rank, E, C);
    deg_kernel<<<nB, 256, 0, stream>>>(bh, deg, N);
    scan_kernel<<<1, 1024, 0, stream>>>(deg, rowptr, N);
    base_kernel<<<nB, 256, 0, stream>>>(bh, rowptr, N);
    scatter_kernel<<<NP * 8, 256, 0, stream>>>(src, dst, rank, bh, ssrc, N, E, C);
    agg_kernel<<<(N + 15) / 16, 256, 0, stream>>>(Qu, KVu, Rb, rowptr, ssrc,
                                                  gamma, beta, out, N);
}